// Round 13
// baseline (4908.854 us; speedup 1.0000x reference)
//
#include <hip/hip_runtime.h>

typedef short short8 __attribute__((ext_vector_type(8)));
typedef float f32x4 __attribute__((ext_vector_type(4)));
typedef float f32x16 __attribute__((ext_vector_type(16)));
typedef int i32x4 __attribute__((ext_vector_type(4)));
typedef unsigned short u16;

#define NBLK 256
#define BDIM 512
#define BB 64
#define TT 512
#define II 512
#define HH 1024
#define NCLS 1000
#define HBUF (BB*HH)

__device__ __forceinline__ u16 f2bf(float f) {
  union { float f; unsigned u; } v; v.f = f;
  unsigned u = v.u;
  u += 0x7fffu + ((u >> 16) & 1u);   // RNE
  return (u16)(u >> 16);
}

__device__ __forceinline__ short8 cvt8(f32x4 a, f32x4 b) {
  short8 v;
  v[0] = (short)f2bf(a[0]); v[1] = (short)f2bf(a[1]);
  v[2] = (short)f2bf(a[2]); v[3] = (short)f2bf(a[3]);
  v[4] = (short)f2bf(b[0]); v[5] = (short)f2bf(b[1]);
  v[6] = (short)f2bf(b[2]); v[7] = (short)f2bf(b[3]);
  return v;
}

__device__ __forceinline__ unsigned ld_rlx(const unsigned* p) {
  return __hip_atomic_load(p, __ATOMIC_RELAXED, __HIP_MEMORY_SCOPE_AGENT);
}
__device__ __forceinline__ void st_rlx(unsigned* p, unsigned v) {
  __hip_atomic_store(p, v, __ATOMIC_RELAXED, __HIP_MEMORY_SCOPE_AGENT);
}
// wave-level flag wait: all lanes poll one address (single coalesced request)
__device__ __forceinline__ void wave_wait_ge(const unsigned* p, unsigned tgt) {
  while (ld_rlx(p) < tgt) __builtin_amdgcn_s_sleep(1);
}

// x f32 -> bf16 pre-pass (tier A)
__global__ void cvt_x(const float* __restrict__ x, u16* __restrict__ xb, int n8) {
  int i = blockIdx.x * blockDim.x + threadIdx.x;
  const int stride = gridDim.x * blockDim.x;
  for (; i < n8; i += stride) {
    f32x4 a = ((const f32x4*)x)[2 * i];
    f32x4 b = ((const f32x4*)x)[2 * i + 1];
    ((short8*)xb)[i] = cvt8(a, b);
  }
}

// ---- coherent fragment run: 2-deep pipelined batches, counted vmcnt ----
#define ISSUE8(arr, OFF)                                                     \
  _Pragma("unroll") for (int i_ = 0; i_ < 8; ++i_)                           \
    asm volatile("global_load_dwordx4 %0, %1, off sc0 sc1"                   \
                 : "=v"(arr[i_]) : "v"(lanep + ((OFF) + i_) * 16));
#define MFMA8(arr, OFF)                                                      \
  _Pragma("unroll") for (int i_ = 0; i_ < 8; ++i_) {                         \
    union { i32x4 q; short8 s; } u_; u_.q = arr[i_];                         \
    acc = __builtin_amdgcn_mfma_f32_32x32x16_bf16(u_.s, breg[B0 + (OFF) + i_],\
                                                  acc, 0, 0, 0); }
#define VMWAIT0 asm volatile("s_waitcnt vmcnt(0)" ::: "memory")
#define VMWAIT8 asm volatile("s_waitcnt vmcnt(8)" ::: "memory")
#define SCHEDB  __builtin_amdgcn_sched_barrier(0)

template<int N, int B0, int MH>
__device__ __forceinline__ void run_coh(const u16* lanep,
                                        const short8 (&breg)[MH], f32x16& acc) {
  static_assert(N == 8 || N == 16 || N == 24 || N == 32, "");
  i32x4 avA[8], avB[8];
  if constexpr (N == 8) {
    ISSUE8(avA, 0);
    VMWAIT0; SCHEDB; MFMA8(avA, 0);
  } else if constexpr (N == 16) {
    ISSUE8(avA, 0); ISSUE8(avB, 8);
    VMWAIT8; SCHEDB; MFMA8(avA, 0);
    VMWAIT0; SCHEDB; MFMA8(avB, 8);
  } else if constexpr (N == 24) {
    ISSUE8(avA, 0); ISSUE8(avB, 8);
    VMWAIT8; SCHEDB; MFMA8(avA, 0); ISSUE8(avA, 16);
    VMWAIT8; SCHEDB; MFMA8(avB, 8);
    VMWAIT0; SCHEDB; MFMA8(avA, 16);
  } else {
    ISSUE8(avA, 0); ISSUE8(avB, 8);
    VMWAIT8; SCHEDB; MFMA8(avA, 0); ISSUE8(avA, 16);
    VMWAIT8; SCHEDB; MFMA8(avB, 8); ISSUE8(avB, 24);
    VMWAIT8; SCHEDB; MFMA8(avA, 16);
    VMWAIT0; SCHEDB; MFMA8(avB, 24);
  }
}

// plain cached bf16 run (L0 x-section, tier A)
template<int N, int B0, int MH>
__device__ __forceinline__ void run_pb(const u16* lanep,
                                       const short8 (&breg)[MH], f32x16& acc) {
#pragma unroll
  for (int i = 0; i < N; ++i) {
    short8 av = *(const short8*)(lanep + i * 16);
    acc = __builtin_amdgcn_mfma_f32_32x32x16_bf16(av, breg[B0 + i], acc, 0, 0, 0);
  }
}

// plain cached f32 run + convert (L0 x-section, tier B)
template<int N, int B0, int MH>
__device__ __forceinline__ void run_pf(const float* lanep,
                                       const short8 (&breg)[MH], f32x16& acc) {
#pragma unroll
  for (int i = 0; i < N; ++i) {
    short8 av = cvt8(*(const f32x4*)(lanep + i * 16),
                     *(const f32x4*)(lanep + i * 16 + 4));
    acc = __builtin_amdgcn_mfma_f32_32x32x16_bf16(av, breg[B0 + i], acc, 0, 0, 0);
  }
}

// Decoupled persistent 2-layer LSTM, short-critical-chain edition.
// Blocks [0,128)=L0, [128,256)=L1; block = 16 units (64 gate rows) x 32 batch
// rows; 8 waves = 2 gate-row-groups x 4 K-quarters. NEW vs R12: every wave owns
// a quarter of EACH K-section (input + recurrent) instead of half the waves
// owning the whole recurrent section -> the post-flag critical load chain is
// 16 frags (2 batches, issued upfront) instead of 32 (4 batches). The input
// section runs before the recurrent flag-wait and is effectively free.
template<bool XBF>
__global__ __launch_bounds__(BDIM, 2) void lstm2_fused(
    const float* __restrict__ x, const u16* __restrict__ xb,
    const float* __restrict__ Wih0, const float* __restrict__ Whh0,
    const float* __restrict__ bih0, const float* __restrict__ bhh0,
    const float* __restrict__ Wih1, const float* __restrict__ Whh1,
    const float* __restrict__ bih1, const float* __restrict__ bhh1,
    u16* __restrict__ ring,          // 3 x [64][1024] bf16 (h0)
    u16* __restrict__ h1buf,         // 2 x [64][1024] bf16 (h1)
    float* __restrict__ h1f,
    unsigned* __restrict__ bar)
{
  __shared__ float g4[4][32][68];        // 34.8 KB K-partial buffer (padded)
  __shared__ float blds[64];             // fused biases (64 gate rows)

  const bool isL1 = (blockIdx.x >= 128);
  const int wgl = isL1 ? (int)blockIdx.x - 128 : (int)blockIdx.x;
  const int ug = wgl >> 1, bg = wgl & 1;
  const int j0 = ug * 16;                // first hidden unit owned
  const int rowoff = bg * 32;            // first batch row owned

  const int lane = threadIdx.x & 63;
  const int wid = threadIdx.x >> 6;      // 8 waves
  const int gr = wid & 1, kq = wid >> 1; // 2 gate-row-groups x 4 K-quarters
  const int sub8 = (lane >> 5) << 3;     // k sub-offset within 16-k fragment
  const int rl = gr * 32 + (lane & 31);  // gate-row local [0,64) = gate*16+unit
  const int rglob = ((rl >> 4) << 10) + j0 + (rl & 15);
  const int arow = rowoff + (lane & 31); // A (batch) row this lane loads

  if (threadIdx.x < 64) {                // biases
    int u = threadIdx.x;
    int r = ((u >> 4) << 10) + j0 + (u & 15);
    blds[u] = isL1 ? (bih1[r] + bhh1[r]) : (bih0[r] + bhh0[r]);
  }
  __syncthreads();

  const int tb = threadIdx.x >> 4;       // tail batch row local [0,32)
  const int tu = threadIdx.x & 15;       // tail unit [0,16)

  unsigned* const arrA = bar;            // L0 arrive
  unsigned* const relA = bar + 64;       // "h0(t) visible" <=> relA >= t+1
  unsigned* const arrB = bar + 128;      // L1 arrive
  unsigned* const relB = bar + 192;      // "h1(t) visible" <=> relB >= t+1

  float c_state = 0.f;

  // tail: combine 4 K-partials, gates, c/h update, coherent h store, arrive
  auto step_tail = [&](const f32x16& acc, u16* hout, unsigned ringtgt, bool wf,
                       unsigned* arr, unsigned* rel, int t) {
    const int col = lane & 31;
    const int rbase = (lane >> 5) << 2;
#pragma unroll
    for (int r = 0; r < 16; ++r) {
      int brow = rbase + (r & 3) + ((r >> 2) << 3);   // C/D row (batch, [0,32))
      g4[kq][brow][gr * 32 + col] = acc[r];
    }
    __syncthreads();
    float gv[4];
#pragma unroll
    for (int g = 0; g < 4; ++g)
      gv[g] = g4[0][tb][g * 16 + tu] + g4[1][tb][g * 16 + tu]
            + g4[2][tb][g * 16 + tu] + g4[3][tb][g * 16 + tu]
            + blds[g * 16 + tu];
    float gi = 1.f / (1.f + __expf(-gv[0]));
    float gf = 1.f / (1.f + __expf(-gv[1]));
    float e2 = __expf(2.f * fminf(15.f, fmaxf(-15.f, gv[2])));
    float gg = (e2 - 1.f) / (e2 + 1.f);
    float go = 1.f / (1.f + __expf(-gv[3]));
    c_state = gf * c_state + gi * gg;
    float e2c = __expf(2.f * fminf(15.f, fmaxf(-15.f, c_state)));
    float th = (e2c - 1.f) / (e2c + 1.f);
    float hval = go * th;
    if (ringtgt) wave_wait_ge(relB, ringtgt);   // L0 ring slot reuse guard
    unsigned hu = (unsigned)f2bf(hval);
    unsigned nbv = (unsigned)__shfl_xor((int)hu, 1);
    if ((tu & 1) == 0) {
      unsigned packed = hu | (nbv << 16);
      unsigned* dst = (unsigned*)(hout + (size_t)(rowoff + tb) * HH + j0 + tu);
      st_rlx(dst, packed);
    }
    if (wf) h1f[(size_t)(rowoff + tb) * HH + j0 + tu] = hval;
    __syncthreads();                    // drains h stores before arrive
    if (threadIdx.x == 0) {             // arrive; 128th poster releases. NO wait.
      unsigned old = atomicAdd(arr, 1u);
      if (old == (unsigned)(128 * (t + 1) - 1)) st_rlx(rel, (unsigned)(t + 1));
    }
  };

  if (!isL1) {
    // ======= layer 0: per wave = x eighth (8 frags) + h0 quarter (16 frags) ==
    short8 breg[24];
#pragma unroll
    for (int i = 0; i < 8; ++i) {        // frags 0-7: Wih0 cols kq*128 ..
      int k = kq * 128 + i * 16 + sub8;
      breg[i] = cvt8(*(const f32x4*)(Wih0 + (size_t)rglob * II + k),
                     *(const f32x4*)(Wih0 + (size_t)rglob * II + k + 4));
    }
#pragma unroll
    for (int i = 0; i < 16; ++i) {       // frags 8-23: Whh0 cols kq*256 ..
      int k = kq * 256 + i * 16 + sub8;
      breg[8 + i] = cvt8(*(const f32x4*)(Whh0 + (size_t)rglob * HH + k),
                         *(const f32x4*)(Whh0 + (size_t)rglob * HH + k + 4));
    }

    for (int t = 0; t < TT; ++t) {
      f32x16 acc = {};
      // x section (plain cached; no flag needed)
      if (XBF) {
        const u16* xl = xb + (size_t)arow * ((size_t)TT * II) + (size_t)t * II
                        + kq * 128 + sub8;
        run_pb<8, 0>(xl, breg, acc);
      } else {
        const float* xl = x + (size_t)arow * ((size_t)TT * II) + (size_t)t * II
                          + kq * 128 + sub8;
        run_pf<8, 0>(xl, breg, acc);
      }
      // h0 recurrent quarter (critical): 16 frags issued upfront after flag
      wave_wait_ge(relA, (unsigned)t);
      {
        const u16* hb = ring + (size_t)((t + 2) % 3) * HBUF + (size_t)arow * HH
                        + kq * 256 + sub8;
        run_coh<16, 8>(hb, breg, acc);
      }
      step_tail(acc, ring + (size_t)(t % 3) * HBUF,
                (t >= 3) ? (unsigned)(t - 2) : 0u, false, arrA, relA, t);
    }
  } else {
    // ======= layer 1: per wave = h0 quarter (16) + h1 quarter (16, critical) ==
    short8 breg[32];
#pragma unroll
    for (int i = 0; i < 16; ++i) {       // frags 0-15: Wih1 cols kq*256 ..
      int k = kq * 256 + i * 16 + sub8;
      breg[i] = cvt8(*(const f32x4*)(Wih1 + (size_t)rglob * HH + k),
                     *(const f32x4*)(Wih1 + (size_t)rglob * HH + k + 4));
    }
#pragma unroll
    for (int i = 0; i < 16; ++i) {       // frags 16-31: Whh1 cols kq*256 ..
      int k = kq * 256 + i * 16 + sub8;
      breg[16 + i] = cvt8(*(const f32x4*)(Whh1 + (size_t)rglob * HH + k),
                          *(const f32x4*)(Whh1 + (size_t)rglob * HH + k + 4));
    }

    for (int t = 0; t < TT; ++t) {
      f32x16 acc = {};
      // input section: h0(t) = ring slot t%3 (L0 runs ahead; wait ~free)
      wave_wait_ge(relA, (unsigned)(t + 1));
      {
        const u16* lp = ring + (size_t)(t % 3) * HBUF + (size_t)arow * HH
                        + kq * 256 + sub8;
        run_coh<16, 0>(lp, breg, acc);
      }
      // recurrent quarter (critical): h1(t-1), 16 frags upfront after flag
      wave_wait_ge(relB, (unsigned)t);
      {
        const u16* lp = h1buf + (size_t)((t + 1) & 1) * HBUF
                        + (size_t)arow * HH + kq * 256 + sub8;
        run_coh<16, 16>(lp, breg, acc);
      }
      step_tail(acc, h1buf + (size_t)(t & 1) * HBUF, 0u, t == TT - 1,
                arrB, relB, t);
    }
  }
}

// out[b][c] = sum_k h1f[b][k] * Wd[c][k] + bd[c]   (all f32)
__global__ void dense_out(const float* __restrict__ h1, const float* __restrict__ Wd,
                          const float* __restrict__ bd, float* __restrict__ out)
{
  const int b  = threadIdx.x & 63;
  const int cl = threadIdx.x >> 6;
  const int cc = blockIdx.x * 4 + cl;    // class (250*4 = 1000)
  float acc = 0.f;
  const float* hrow = h1 + (size_t)b * HH;
  const float* wrow = Wd + (size_t)cc * HH;
#pragma unroll 8
  for (int k = 0; k < HH; k += 4) {
    f32x4 hv = *(const f32x4*)(hrow + k);
    f32x4 wv = *(const f32x4*)(wrow + k);
    acc += hv[0] * wv[0] + hv[1] * wv[1] + hv[2] * wv[2] + hv[3] * wv[3];
  }
  out[(size_t)b * NCLS + cc] = acc + bd[cc];
}

extern "C" void kernel_launch(void* const* d_in, const int* in_sizes, int n_in,
                              void* d_out, int out_size, void* d_ws, size_t ws_size,
                              hipStream_t stream)
{
  (void)in_sizes; (void)n_in; (void)out_size;
  const float* x    = (const float*)d_in[0];
  const float* Wih0 = (const float*)d_in[1];
  const float* Whh0 = (const float*)d_in[2];
  const float* bih0 = (const float*)d_in[3];
  const float* bhh0 = (const float*)d_in[4];
  const float* Wih1 = (const float*)d_in[5];
  const float* Whh1 = (const float*)d_in[6];
  const float* bih1 = (const float*)d_in[7];
  const float* bhh1 = (const float*)d_in[8];
  const float* Wd   = (const float*)d_in[9];
  const float* bd   = (const float*)d_in[10];

  unsigned* bar = (unsigned*)d_ws;                       // 4 KB flag/counter lines
  float* h1f  = (float*)((char*)d_ws + 4096);            // 256 KB
  u16* h1buf  = (u16*)((char*)d_ws + 272 * 1024);        // 2 x 128 KB
  u16* ring   = (u16*)((char*)d_ws + 528 * 1024);        // 3 x 128 KB
  u16* xb     = (u16*)((char*)d_ws + (1u << 20));        // 33.6 MB (tier A)

  const size_t needA = (1u << 20) + (size_t)BB * TT * II * 2;
  const bool tierA = (ws_size >= needA);

  // zero flags + h buffers every launch (graph-replay deterministic)
  hipMemsetAsync(d_ws, 0, 912 * 1024, stream);

  if (tierA) {
    hipLaunchKernelGGL(cvt_x, dim3(2048), dim3(256), 0, stream,
                       x, xb, (int)((size_t)BB * TT * II / 8));
    hipLaunchKernelGGL((lstm2_fused<true>), dim3(NBLK), dim3(BDIM), 0, stream,
                       x, xb, Wih0, Whh0, bih0, bhh0, Wih1, Whh1, bih1, bhh1,
                       ring, h1buf, h1f, bar);
  } else {
    hipLaunchKernelGGL((lstm2_fused<false>), dim3(NBLK), dim3(BDIM), 0, stream,
                       x, xb, Wih0, Whh0, bih0, bhh0, Wih1, Whh1, bih1, bhh1,
                       ring, h1buf, h1f, bar);
  }
  hipLaunchKernelGGL(dense_out, dim3(250), dim3(256), 0, stream, h1f, Wd, bd,
                     (float*)d_out);
}

// Round 14
// 4720.386 us; speedup vs baseline: 1.0399x; 1.0399x over previous
//
#include <hip/hip_runtime.h>

typedef short short8 __attribute__((ext_vector_type(8)));
typedef float f32x4 __attribute__((ext_vector_type(4)));
typedef float f32x16 __attribute__((ext_vector_type(16)));
typedef int i32x4 __attribute__((ext_vector_type(4)));
typedef unsigned short u16;

#define NBLK 256
#define BDIM 512
#define BB 64
#define TT 512
#define II 512
#define HH 1024
#define NCLS 1000
#define HBUF (BB*HH)

__device__ __forceinline__ u16 f2bf(float f) {
  union { float f; unsigned u; } v; v.f = f;
  unsigned u = v.u;
  u += 0x7fffu + ((u >> 16) & 1u);   // RNE
  return (u16)(u >> 16);
}

__device__ __forceinline__ short8 cvt8(f32x4 a, f32x4 b) {
  short8 v;
  v[0] = (short)f2bf(a[0]); v[1] = (short)f2bf(a[1]);
  v[2] = (short)f2bf(a[2]); v[3] = (short)f2bf(a[3]);
  v[4] = (short)f2bf(b[0]); v[5] = (short)f2bf(b[1]);
  v[6] = (short)f2bf(b[2]); v[7] = (short)f2bf(b[3]);
  return v;
}

__device__ __forceinline__ unsigned ld_rlx(const unsigned* p) {
  return __hip_atomic_load(p, __ATOMIC_RELAXED, __HIP_MEMORY_SCOPE_AGENT);
}
__device__ __forceinline__ void st_rlx(unsigned* p, unsigned v) {
  __hip_atomic_store(p, v, __ATOMIC_RELAXED, __HIP_MEMORY_SCOPE_AGENT);
}
// wave-level flag wait on this block's mirror line (single coalesced request)
__device__ __forceinline__ void wave_wait_ge(const unsigned* p, unsigned tgt) {
  while (ld_rlx(p) < tgt) __builtin_amdgcn_s_sleep(1);
}
// closer posts the release value to all 8 mirror lines
__device__ __forceinline__ void post_rel8(unsigned* rel, unsigned v) {
#pragma unroll
  for (int m = 0; m < 8; ++m) st_rlx(rel + m * 32, v);
}

// x f32 -> bf16 pre-pass (tier A)
__global__ void cvt_x(const float* __restrict__ x, u16* __restrict__ xb, int n8) {
  int i = blockIdx.x * blockDim.x + threadIdx.x;
  const int stride = gridDim.x * blockDim.x;
  for (; i < n8; i += stride) {
    f32x4 a = ((const f32x4*)x)[2 * i];
    f32x4 b = ((const f32x4*)x)[2 * i + 1];
    ((short8*)xb)[i] = cvt8(a, b);
  }
}

// ---- coherent fragment run: 2-deep pipelined batches, counted vmcnt ----
#define ISSUE8(arr, OFF)                                                     \
  _Pragma("unroll") for (int i_ = 0; i_ < 8; ++i_)                           \
    asm volatile("global_load_dwordx4 %0, %1, off sc0 sc1"                   \
                 : "=v"(arr[i_]) : "v"(lanep + ((OFF) + i_) * 16));
#define MFMA8(arr, OFF)                                                      \
  _Pragma("unroll") for (int i_ = 0; i_ < 8; ++i_) {                         \
    union { i32x4 q; short8 s; } u_; u_.q = arr[i_];                         \
    acc = __builtin_amdgcn_mfma_f32_32x32x16_bf16(u_.s, breg[B0 + (OFF) + i_],\
                                                  acc, 0, 0, 0); }
#define VMWAIT0 asm volatile("s_waitcnt vmcnt(0)" ::: "memory")
#define VMWAIT8 asm volatile("s_waitcnt vmcnt(8)" ::: "memory")
#define SCHEDB  __builtin_amdgcn_sched_barrier(0)

template<int N, int B0, int MH>
__device__ __forceinline__ void run_coh(const u16* lanep,
                                        const short8 (&breg)[MH], f32x16& acc) {
  static_assert(N == 8 || N == 16 || N == 24 || N == 32, "");
  i32x4 avA[8], avB[8];
  if constexpr (N == 8) {
    ISSUE8(avA, 0);
    VMWAIT0; SCHEDB; MFMA8(avA, 0);
  } else if constexpr (N == 16) {
    ISSUE8(avA, 0); ISSUE8(avB, 8);
    VMWAIT8; SCHEDB; MFMA8(avA, 0);
    VMWAIT0; SCHEDB; MFMA8(avB, 8);
  } else if constexpr (N == 24) {
    ISSUE8(avA, 0); ISSUE8(avB, 8);
    VMWAIT8; SCHEDB; MFMA8(avA, 0); ISSUE8(avA, 16);
    VMWAIT8; SCHEDB; MFMA8(avB, 8);
    VMWAIT0; SCHEDB; MFMA8(avA, 16);
  } else {
    ISSUE8(avA, 0); ISSUE8(avB, 8);
    VMWAIT8; SCHEDB; MFMA8(avA, 0); ISSUE8(avA, 16);
    VMWAIT8; SCHEDB; MFMA8(avB, 8); ISSUE8(avB, 24);
    VMWAIT8; SCHEDB; MFMA8(avA, 16);
    VMWAIT0; SCHEDB; MFMA8(avB, 24);
  }
}

// plain cached bf16 run (L0 x-section, tier A)
template<int N, int B0, int MH>
__device__ __forceinline__ void run_pb(const u16* lanep,
                                       const short8 (&breg)[MH], f32x16& acc) {
#pragma unroll
  for (int i = 0; i < N; ++i) {
    short8 av = *(const short8*)(lanep + i * 16);
    acc = __builtin_amdgcn_mfma_f32_32x32x16_bf16(av, breg[B0 + i], acc, 0, 0, 0);
  }
}

// plain cached f32 run + convert (L0 x-section, tier B)
template<int N, int B0, int MH>
__device__ __forceinline__ void run_pf(const float* lanep,
                                       const short8 (&breg)[MH], f32x16& acc) {
#pragma unroll
  for (int i = 0; i < N; ++i) {
    short8 av = cvt8(*(const f32x4*)(lanep + i * 16),
                     *(const f32x4*)(lanep + i * 16 + 4));
    acc = __builtin_amdgcn_mfma_f32_32x32x16_bf16(av, breg[B0 + i], acc, 0, 0, 0);
  }
}

// Decoupled persistent 2-layer LSTM — R12 structure + 8-way mirrored release
// flags. Blocks [0,128)=L0, [128,256)=L1; block = 16 units (64 gate rows) x
// 32 batch rows; 8 waves = 2 gate-row-groups x 4 K-quarters. Release flags are
// replicated to 8 separate 128B lines; each block polls only line blockIdx&7,
// cutting per-line poll contention 8x.
template<bool XBF>
__global__ __launch_bounds__(BDIM, 2) void lstm2_fused(
    const float* __restrict__ x, const u16* __restrict__ xb,
    const float* __restrict__ Wih0, const float* __restrict__ Whh0,
    const float* __restrict__ bih0, const float* __restrict__ bhh0,
    const float* __restrict__ Wih1, const float* __restrict__ Whh1,
    const float* __restrict__ bih1, const float* __restrict__ bhh1,
    u16* __restrict__ ring,          // 3 x [64][1024] bf16 (h0)
    u16* __restrict__ h1buf,         // 2 x [64][1024] bf16 (h1)
    float* __restrict__ h1f,
    unsigned* __restrict__ bar)
{
  __shared__ float g4[4][32][68];        // 34.8 KB K-partial buffer (padded)
  __shared__ float blds[64];             // fused biases (64 gate rows)

  const bool isL1 = (blockIdx.x >= 128);
  const int wgl = isL1 ? (int)blockIdx.x - 128 : (int)blockIdx.x;
  const int ug = wgl >> 1, bg = wgl & 1;
  const int j0 = ug * 16;                // first hidden unit owned
  const int rowoff = bg * 32;            // first batch row owned
  const int mir = ((int)blockIdx.x & 7) * 32;   // this block's mirror offset

  const int lane = threadIdx.x & 63;
  const int wid = threadIdx.x >> 6;      // 8 waves
  const int gr = wid & 1, kq = wid >> 1; // 2 gate-row-groups x 4 K-quarters
  const int sub8 = (lane >> 5) << 3;     // k sub-offset within 16-k fragment
  const int rl = gr * 32 + (lane & 31);  // gate-row local [0,64) = gate*16+unit
  const int rglob = ((rl >> 4) << 10) + j0 + (rl & 15);
  const int arow = rowoff + (lane & 31); // A (batch) row this lane loads

  if (threadIdx.x < 64) {                // biases
    int u = threadIdx.x;
    int r = ((u >> 4) << 10) + j0 + (u & 15);
    blds[u] = isL1 ? (bih1[r] + bhh1[r]) : (bih0[r] + bhh0[r]);
  }
  __syncthreads();

  const int tb = threadIdx.x >> 4;       // tail batch row local [0,32)
  const int tu = threadIdx.x & 15;       // tail unit [0,16)

  unsigned* const arrA = bar;            // L0 arrive counter (line 0)
  unsigned* const arrB = bar + 32;       // L1 arrive counter (line 1)
  unsigned* const relA = bar + 64;       // L0 release: 8 mirror lines
  unsigned* const relB = bar + 64 + 256; // L1 release: 8 mirror lines

  float c_state = 0.f;

  // tail: combine 4 K-partials, gates, c/h update, coherent h store, arrive
  auto step_tail = [&](const f32x16& acc, u16* hout, unsigned ringtgt, bool wf,
                       unsigned* arr, unsigned* rel, int t) {
    const int col = lane & 31;
    const int rbase = (lane >> 5) << 2;
#pragma unroll
    for (int r = 0; r < 16; ++r) {
      int brow = rbase + (r & 3) + ((r >> 2) << 3);   // C/D row (batch, [0,32))
      g4[kq][brow][gr * 32 + col] = acc[r];
    }
    __syncthreads();
    float gv[4];
#pragma unroll
    for (int g = 0; g < 4; ++g)
      gv[g] = g4[0][tb][g * 16 + tu] + g4[1][tb][g * 16 + tu]
            + g4[2][tb][g * 16 + tu] + g4[3][tb][g * 16 + tu]
            + blds[g * 16 + tu];
    float gi = 1.f / (1.f + __expf(-gv[0]));
    float gf = 1.f / (1.f + __expf(-gv[1]));
    float e2 = __expf(2.f * fminf(15.f, fmaxf(-15.f, gv[2])));
    float gg = (e2 - 1.f) / (e2 + 1.f);
    float go = 1.f / (1.f + __expf(-gv[3]));
    c_state = gf * c_state + gi * gg;
    float e2c = __expf(2.f * fminf(15.f, fmaxf(-15.f, c_state)));
    float th = (e2c - 1.f) / (e2c + 1.f);
    float hval = go * th;
    if (ringtgt) wave_wait_ge(relB + mir, ringtgt);  // L0 ring slot reuse guard
    unsigned hu = (unsigned)f2bf(hval);
    unsigned nbv = (unsigned)__shfl_xor((int)hu, 1);
    if ((tu & 1) == 0) {
      unsigned packed = hu | (nbv << 16);
      unsigned* dst = (unsigned*)(hout + (size_t)(rowoff + tb) * HH + j0 + tu);
      st_rlx(dst, packed);
    }
    if (wf) h1f[(size_t)(rowoff + tb) * HH + j0 + tu] = hval;
    __syncthreads();                    // drains h stores before arrive
    if (threadIdx.x == 0) {             // arrive; 128th poster releases. NO wait.
      unsigned old = atomicAdd(arr, 1u);
      if (old == (unsigned)(128 * (t + 1) - 1)) post_rel8(rel, (unsigned)(t + 1));
    }
  };

  if (!isL1) {
    // ======= layer 0: K=1536 (x 512 | h0 1024), 24 frags/wave ================
    short8 breg[24];
#pragma unroll
    for (int i = 0; i < 24; ++i) {
      int k = kq * 384 + i * 16 + sub8;
      const float* src = (k < II) ? (Wih0 + (size_t)rglob * II + k)
                                  : (Whh0 + (size_t)rglob * HH + (k - II));
      breg[i] = cvt8(*(const f32x4*)src, *(const f32x4*)(src + 4));
    }

    for (int t = 0; t < TT; ++t) {
      f32x16 acc = {};
      const u16* hb = ring + (size_t)((t + 2) % 3) * HBUF + (size_t)arow * HH;
      if (XBF) {
        const u16* xl = xb + (size_t)arow * ((size_t)TT * II) + (size_t)t * II
                        + kq * 384 + sub8;
        if (kq == 0)      run_pb<24, 0>(xl, breg, acc);
        else if (kq == 1) { run_pb<8, 0>(xl, breg, acc);
                            wave_wait_ge(relA + mir, (unsigned)t);
                            run_coh<16, 8>(hb + 0 + sub8, breg, acc); }
        else if (kq == 2) { wave_wait_ge(relA + mir, (unsigned)t);
                            run_coh<24, 0>(hb + 256 + sub8, breg, acc); }
        else              { wave_wait_ge(relA + mir, (unsigned)t);
                            run_coh<24, 0>(hb + 640 + sub8, breg, acc); }
      } else {
        const float* xl = x + (size_t)arow * ((size_t)TT * II) + (size_t)t * II
                          + kq * 384 + sub8;
        if (kq == 0)      run_pf<24, 0>(xl, breg, acc);
        else if (kq == 1) { run_pf<8, 0>(xl, breg, acc);
                            wave_wait_ge(relA + mir, (unsigned)t);
                            run_coh<16, 8>(hb + 0 + sub8, breg, acc); }
        else if (kq == 2) { wave_wait_ge(relA + mir, (unsigned)t);
                            run_coh<24, 0>(hb + 256 + sub8, breg, acc); }
        else              { wave_wait_ge(relA + mir, (unsigned)t);
                            run_coh<24, 0>(hb + 640 + sub8, breg, acc); }
      }
      step_tail(acc, ring + (size_t)(t % 3) * HBUF,
                (t >= 3) ? (unsigned)(t - 2) : 0u, false, arrA, relA, t);
    }
  } else {
    // ======= layer 1: K=2048 (h0 1024 | h1 1024), 32 frags/wave ==============
    short8 breg[32];
#pragma unroll
    for (int i = 0; i < 32; ++i) {
      int k = kq * 512 + i * 16 + sub8;
      const float* src = (k < HH) ? (Wih1 + (size_t)rglob * HH + k)
                                  : (Whh1 + (size_t)rglob * HH + (k - HH));
      breg[i] = cvt8(*(const f32x4*)src, *(const f32x4*)(src + 4));
    }

    for (int t = 0; t < TT; ++t) {
      f32x16 acc = {};
      if (kq < 2) {                      // input: h0(t) = ring slot t%3
        wave_wait_ge(relA + mir, (unsigned)(t + 1));
        const u16* lp = ring + (size_t)(t % 3) * HBUF + (size_t)arow * HH
                        + kq * 512 + sub8;
        run_coh<32, 0>(lp, breg, acc);
      } else {                           // recurrent: h1(t-1)
        wave_wait_ge(relB + mir, (unsigned)t);
        const u16* lp = h1buf + (size_t)((t + 1) & 1) * HBUF
                        + (size_t)arow * HH + (kq - 2) * 512 + sub8;
        run_coh<32, 0>(lp, breg, acc);
      }
      step_tail(acc, h1buf + (size_t)(t & 1) * HBUF, 0u, t == TT - 1,
                arrB, relB, t);
    }
  }
}

// out[b][c] = sum_k h1f[b][k] * Wd[c][k] + bd[c]   (all f32)
__global__ void dense_out(const float* __restrict__ h1, const float* __restrict__ Wd,
                          const float* __restrict__ bd, float* __restrict__ out)
{
  const int b  = threadIdx.x & 63;
  const int cl = threadIdx.x >> 6;
  const int cc = blockIdx.x * 4 + cl;    // class (250*4 = 1000)
  float acc = 0.f;
  const float* hrow = h1 + (size_t)b * HH;
  const float* wrow = Wd + (size_t)cc * HH;
#pragma unroll 8
  for (int k = 0; k < HH; k += 4) {
    f32x4 hv = *(const f32x4*)(hrow + k);
    f32x4 wv = *(const f32x4*)(wrow + k);
    acc += hv[0] * wv[0] + hv[1] * wv[1] + hv[2] * wv[2] + hv[3] * wv[3];
  }
  out[(size_t)b * NCLS + cc] = acc + bd[cc];
}

extern "C" void kernel_launch(void* const* d_in, const int* in_sizes, int n_in,
                              void* d_out, int out_size, void* d_ws, size_t ws_size,
                              hipStream_t stream)
{
  (void)in_sizes; (void)n_in; (void)out_size;
  const float* x    = (const float*)d_in[0];
  const float* Wih0 = (const float*)d_in[1];
  const float* Whh0 = (const float*)d_in[2];
  const float* bih0 = (const float*)d_in[3];
  const float* bhh0 = (const float*)d_in[4];
  const float* Wih1 = (const float*)d_in[5];
  const float* Whh1 = (const float*)d_in[6];
  const float* bih1 = (const float*)d_in[7];
  const float* bhh1 = (const float*)d_in[8];
  const float* Wd   = (const float*)d_in[9];
  const float* bd   = (const float*)d_in[10];

  unsigned* bar = (unsigned*)d_ws;                       // 4 KB flag/counter lines
  float* h1f  = (float*)((char*)d_ws + 4096);            // 256 KB
  u16* h1buf  = (u16*)((char*)d_ws + 272 * 1024);        // 2 x 128 KB
  u16* ring   = (u16*)((char*)d_ws + 528 * 1024);        // 3 x 128 KB
  u16* xb     = (u16*)((char*)d_ws + (1u << 20));        // 33.6 MB (tier A)

  const size_t needA = (1u << 20) + (size_t)BB * TT * II * 2;
  const bool tierA = (ws_size >= needA);

  // zero flags + h buffers every launch (graph-replay deterministic)
  hipMemsetAsync(d_ws, 0, 912 * 1024, stream);

  if (tierA) {
    hipLaunchKernelGGL(cvt_x, dim3(2048), dim3(256), 0, stream,
                       x, xb, (int)((size_t)BB * TT * II / 8));
    hipLaunchKernelGGL((lstm2_fused<true>), dim3(NBLK), dim3(BDIM), 0, stream,
                       x, xb, Wih0, Whh0, bih0, bhh0, Wih1, Whh1, bih1, bhh1,
                       ring, h1buf, h1f, bar);
  } else {
    hipLaunchKernelGGL((lstm2_fused<false>), dim3(NBLK), dim3(BDIM), 0, stream,
                       x, xb, Wih0, Whh0, bih0, bhh0, Wih1, Whh1, bih1, bhh1,
                       ring, h1buf, h1f, bar);
  }
  hipLaunchKernelGGL(dense_out, dim3(250), dim3(256), 0, stream, h1f, Wd, bd,
                     (float*)d_out);
}

// Round 15
// 4644.381 us; speedup vs baseline: 1.0569x; 1.0164x over previous
//
#include <hip/hip_runtime.h>

typedef short short8 __attribute__((ext_vector_type(8)));
typedef float f32x4 __attribute__((ext_vector_type(4)));
typedef float f32x16 __attribute__((ext_vector_type(16)));
typedef int i32x4 __attribute__((ext_vector_type(4)));
typedef unsigned short u16;

#define NBLK 256
#define BDIM 512
#define BB 64
#define TT 512
#define II 512
#define HH 1024
#define NCLS 1000
#define HBUF (BB*HH)

__device__ __forceinline__ u16 f2bf(float f) {
  union { float f; unsigned u; } v; v.f = f;
  unsigned u = v.u;
  u += 0x7fffu + ((u >> 16) & 1u);   // RNE
  return (u16)(u >> 16);
}

__device__ __forceinline__ short8 cvt8(f32x4 a, f32x4 b) {
  short8 v;
  v[0] = (short)f2bf(a[0]); v[1] = (short)f2bf(a[1]);
  v[2] = (short)f2bf(a[2]); v[3] = (short)f2bf(a[3]);
  v[4] = (short)f2bf(b[0]); v[5] = (short)f2bf(b[1]);
  v[6] = (short)f2bf(b[2]); v[7] = (short)f2bf(b[3]);
  return v;
}

__device__ __forceinline__ unsigned ld_rlx(const unsigned* p) {
  return __hip_atomic_load(p, __ATOMIC_RELAXED, __HIP_MEMORY_SCOPE_AGENT);
}
__device__ __forceinline__ void st_rlx(unsigned* p, unsigned v) {
  __hip_atomic_store(p, v, __ATOMIC_RELAXED, __HIP_MEMORY_SCOPE_AGENT);
}
// wave-level flag wait: all lanes poll one address (single coalesced request)
__device__ __forceinline__ void wave_wait_ge(const unsigned* p, unsigned tgt) {
  while (ld_rlx(p) < tgt) __builtin_amdgcn_s_sleep(1);
}

// x f32 -> bf16 pre-pass (tier A)
__global__ void cvt_x(const float* __restrict__ x, u16* __restrict__ xb, int n8) {
  int i = blockIdx.x * blockDim.x + threadIdx.x;
  const int stride = gridDim.x * blockDim.x;
  for (; i < n8; i += stride) {
    f32x4 a = ((const f32x4*)x)[2 * i];
    f32x4 b = ((const f32x4*)x)[2 * i + 1];
    ((short8*)xb)[i] = cvt8(a, b);
  }
}

// ---- coherent fragment run: 2-deep pipelined batches, counted vmcnt ----
#define ISSUE8(arr, OFF)                                                     \
  _Pragma("unroll") for (int i_ = 0; i_ < 8; ++i_)                           \
    asm volatile("global_load_dwordx4 %0, %1, off sc0 sc1"                   \
                 : "=v"(arr[i_]) : "v"(lanep + ((OFF) + i_) * 16));
#define MFMA8(arr, OFF)                                                      \
  _Pragma("unroll") for (int i_ = 0; i_ < 8; ++i_) {                         \
    union { i32x4 q; short8 s; } u_; u_.q = arr[i_];                         \
    acc = __builtin_amdgcn_mfma_f32_32x32x16_bf16(u_.s, breg[B0 + (OFF) + i_],\
                                                  acc, 0, 0, 0); }
#define VMWAIT0 asm volatile("s_waitcnt vmcnt(0)" ::: "memory")
#define VMWAIT8 asm volatile("s_waitcnt vmcnt(8)" ::: "memory")
#define SCHEDB  __builtin_amdgcn_sched_barrier(0)

template<int N, int B0, int MH>
__device__ __forceinline__ void run_coh(const u16* lanep,
                                        const short8 (&breg)[MH], f32x16& acc) {
  static_assert(N == 8 || N == 16 || N == 24 || N == 32, "");
  i32x4 avA[8], avB[8];
  if constexpr (N == 8) {
    ISSUE8(avA, 0);
    VMWAIT0; SCHEDB; MFMA8(avA, 0);
  } else if constexpr (N == 16) {
    ISSUE8(avA, 0); ISSUE8(avB, 8);
    VMWAIT8; SCHEDB; MFMA8(avA, 0);
    VMWAIT0; SCHEDB; MFMA8(avB, 8);
  } else if constexpr (N == 24) {
    ISSUE8(avA, 0); ISSUE8(avB, 8);
    VMWAIT8; SCHEDB; MFMA8(avA, 0); ISSUE8(avA, 16);
    VMWAIT8; SCHEDB; MFMA8(avB, 8);
    VMWAIT0; SCHEDB; MFMA8(avA, 16);
  } else {
    ISSUE8(avA, 0); ISSUE8(avB, 8);
    VMWAIT8; SCHEDB; MFMA8(avA, 0); ISSUE8(avA, 16);
    VMWAIT8; SCHEDB; MFMA8(avB, 8); ISSUE8(avB, 24);
    VMWAIT8; SCHEDB; MFMA8(avA, 16);
    VMWAIT0; SCHEDB; MFMA8(avB, 24);
  }
}

// plain cached bf16 run (L0 x-section, tier A)
template<int N, int B0, int MH>
__device__ __forceinline__ void run_pb(const u16* lanep,
                                       const short8 (&breg)[MH], f32x16& acc) {
#pragma unroll
  for (int i = 0; i < N; ++i) {
    short8 av = *(const short8*)(lanep + i * 16);
    acc = __builtin_amdgcn_mfma_f32_32x32x16_bf16(av, breg[B0 + i], acc, 0, 0, 0);
  }
}

// plain cached f32 run + convert (L0 x-section, tier B)
template<int N, int B0, int MH>
__device__ __forceinline__ void run_pf(const float* lanep,
                                       const short8 (&breg)[MH], f32x16& acc) {
#pragma unroll
  for (int i = 0; i < N; ++i) {
    short8 av = cvt8(*(const f32x4*)(lanep + i * 16),
                     *(const f32x4*)(lanep + i * 16 + 4));
    acc = __builtin_amdgcn_mfma_f32_32x32x16_bf16(av, breg[B0 + i], acc, 0, 0, 0);
  }
}

// Decoupled persistent 2-layer LSTM — R12 structure + HIERARCHICAL ARRIVE.
// Blocks [0,128)=L0, [128,256)=L1; block = 16 units (64 gate rows) x 32 batch
// rows; 8 waves = 2 gate-row-groups x 4 K-quarters. Arrive: 8 group counters
// (16 blocks each, separate 128B lines, draining in parallel) -> group closer
// RMWs a root counter -> 8th root arrival posts the SINGLE release word that
// consumers poll (the R9/R12-proven cheap detect). Replaces 128 serialized
// same-line RMWs with ~16-parallel + 8.
template<bool XBF>
__global__ __launch_bounds__(BDIM, 2) void lstm2_fused(
    const float* __restrict__ x, const u16* __restrict__ xb,
    const float* __restrict__ Wih0, const float* __restrict__ Whh0,
    const float* __restrict__ bih0, const float* __restrict__ bhh0,
    const float* __restrict__ Wih1, const float* __restrict__ Whh1,
    const float* __restrict__ bih1, const float* __restrict__ bhh1,
    u16* __restrict__ ring,          // 3 x [64][1024] bf16 (h0)
    u16* __restrict__ h1buf,         // 2 x [64][1024] bf16 (h1)
    float* __restrict__ h1f,
    unsigned* __restrict__ bar)
{
  __shared__ float g4[4][32][68];        // 34.8 KB K-partial buffer (padded)
  __shared__ float blds[64];             // fused biases (64 gate rows)

  const bool isL1 = (blockIdx.x >= 128);
  const int wgl = isL1 ? (int)blockIdx.x - 128 : (int)blockIdx.x;
  const int ug = wgl >> 1, bg = wgl & 1;
  const int j0 = ug * 16;                // first hidden unit owned
  const int rowoff = bg * 32;            // first batch row owned
  const int grp = wgl >> 4;              // arrive group [0,8)

  const int lane = threadIdx.x & 63;
  const int wid = threadIdx.x >> 6;      // 8 waves
  const int gr = wid & 1, kq = wid >> 1; // 2 gate-row-groups x 4 K-quarters
  const int sub8 = (lane >> 5) << 3;     // k sub-offset within 16-k fragment
  const int rl = gr * 32 + (lane & 31);  // gate-row local [0,64) = gate*16+unit
  const int rglob = ((rl >> 4) << 10) + j0 + (rl & 15);
  const int arow = rowoff + (lane & 31); // A (batch) row this lane loads

  if (threadIdx.x < 64) {                // biases
    int u = threadIdx.x;
    int r = ((u >> 4) << 10) + j0 + (u & 15);
    blds[u] = isL1 ? (bih1[r] + bhh1[r]) : (bih0[r] + bhh0[r]);
  }
  __syncthreads();

  const int tb = threadIdx.x >> 4;       // tail batch row local [0,32)
  const int tu = threadIdx.x & 15;       // tail unit [0,16)

  // flag layout (all within 8 KB): per-layer {8 group-arrive lines, root line},
  // plus single release lines.
  unsigned* const arrA  = bar;           // groups at +grp*32, root at +256
  unsigned* const arrB  = bar + 512;     // groups at +grp*32, root at +256
  unsigned* const relA  = bar + 1024;    // single release word (line)
  unsigned* const relB  = bar + 1056;    // single release word (line)

  float c_state = 0.f;

  // tail: combine 4 K-partials, gates, c/h update, coherent h store, arrive
  auto step_tail = [&](const f32x16& acc, u16* hout, unsigned ringtgt, bool wf,
                       unsigned* arr, unsigned* rel, int t) {
    const int col = lane & 31;
    const int rbase = (lane >> 5) << 2;
#pragma unroll
    for (int r = 0; r < 16; ++r) {
      int brow = rbase + (r & 3) + ((r >> 2) << 3);   // C/D row (batch, [0,32))
      g4[kq][brow][gr * 32 + col] = acc[r];
    }
    __syncthreads();
    float gv[4];
#pragma unroll
    for (int g = 0; g < 4; ++g)
      gv[g] = g4[0][tb][g * 16 + tu] + g4[1][tb][g * 16 + tu]
            + g4[2][tb][g * 16 + tu] + g4[3][tb][g * 16 + tu]
            + blds[g * 16 + tu];
    float gi = 1.f / (1.f + __expf(-gv[0]));
    float gf = 1.f / (1.f + __expf(-gv[1]));
    float e2 = __expf(2.f * fminf(15.f, fmaxf(-15.f, gv[2])));
    float gg = (e2 - 1.f) / (e2 + 1.f);
    float go = 1.f / (1.f + __expf(-gv[3]));
    c_state = gf * c_state + gi * gg;
    float e2c = __expf(2.f * fminf(15.f, fmaxf(-15.f, c_state)));
    float th = (e2c - 1.f) / (e2c + 1.f);
    float hval = go * th;
    if (ringtgt) wave_wait_ge(relB, ringtgt);   // L0 ring slot reuse guard
    unsigned hu = (unsigned)f2bf(hval);
    unsigned nbv = (unsigned)__shfl_xor((int)hu, 1);
    if ((tu & 1) == 0) {
      unsigned packed = hu | (nbv << 16);
      unsigned* dst = (unsigned*)(hout + (size_t)(rowoff + tb) * HH + j0 + tu);
      st_rlx(dst, packed);
    }
    if (wf) h1f[(size_t)(rowoff + tb) * HH + j0 + tu] = hval;
    __syncthreads();                    // drains h stores before arrive
    if (threadIdx.x == 0) {             // hierarchical arrive; NO wait here.
      unsigned old = atomicAdd(arr + grp * 32, 1u);
      if (old == (unsigned)(16 * (t + 1) - 1)) {
        unsigned ro = atomicAdd(arr + 256, 1u);
        if (ro == (unsigned)(8 * (t + 1) - 1)) st_rlx(rel, (unsigned)(t + 1));
      }
    }
  };

  if (!isL1) {
    // ======= layer 0: K=1536 (x 512 | h0 1024), 24 frags/wave ================
    short8 breg[24];
#pragma unroll
    for (int i = 0; i < 24; ++i) {
      int k = kq * 384 + i * 16 + sub8;
      const float* src = (k < II) ? (Wih0 + (size_t)rglob * II + k)
                                  : (Whh0 + (size_t)rglob * HH + (k - II));
      breg[i] = cvt8(*(const f32x4*)src, *(const f32x4*)(src + 4));
    }

    for (int t = 0; t < TT; ++t) {
      f32x16 acc = {};
      const u16* hb = ring + (size_t)((t + 2) % 3) * HBUF + (size_t)arow * HH;
      if (XBF) {
        const u16* xl = xb + (size_t)arow * ((size_t)TT * II) + (size_t)t * II
                        + kq * 384 + sub8;
        if (kq == 0)      run_pb<24, 0>(xl, breg, acc);
        else if (kq == 1) { run_pb<8, 0>(xl, breg, acc);
                            wave_wait_ge(relA, (unsigned)t);
                            run_coh<16, 8>(hb + 0 + sub8, breg, acc); }
        else if (kq == 2) { wave_wait_ge(relA, (unsigned)t);
                            run_coh<24, 0>(hb + 256 + sub8, breg, acc); }
        else              { wave_wait_ge(relA, (unsigned)t);
                            run_coh<24, 0>(hb + 640 + sub8, breg, acc); }
      } else {
        const float* xl = x + (size_t)arow * ((size_t)TT * II) + (size_t)t * II
                          + kq * 384 + sub8;
        if (kq == 0)      run_pf<24, 0>(xl, breg, acc);
        else if (kq == 1) { run_pf<8, 0>(xl, breg, acc);
                            wave_wait_ge(relA, (unsigned)t);
                            run_coh<16, 8>(hb + 0 + sub8, breg, acc); }
        else if (kq == 2) { wave_wait_ge(relA, (unsigned)t);
                            run_coh<24, 0>(hb + 256 + sub8, breg, acc); }
        else              { wave_wait_ge(relA, (unsigned)t);
                            run_coh<24, 0>(hb + 640 + sub8, breg, acc); }
      }
      step_tail(acc, ring + (size_t)(t % 3) * HBUF,
                (t >= 3) ? (unsigned)(t - 2) : 0u, false, arrA, relA, t);
    }
  } else {
    // ======= layer 1: K=2048 (h0 1024 | h1 1024), 32 frags/wave ==============
    short8 breg[32];
#pragma unroll
    for (int i = 0; i < 32; ++i) {
      int k = kq * 512 + i * 16 + sub8;
      const float* src = (k < HH) ? (Wih1 + (size_t)rglob * HH + k)
                                  : (Whh1 + (size_t)rglob * HH + (k - HH));
      breg[i] = cvt8(*(const f32x4*)src, *(const f32x4*)(src + 4));
    }

    for (int t = 0; t < TT; ++t) {
      f32x16 acc = {};
      if (kq < 2) {                      // input: h0(t) = ring slot t%3
        wave_wait_ge(relA, (unsigned)(t + 1));
        const u16* lp = ring + (size_t)(t % 3) * HBUF + (size_t)arow * HH
                        + kq * 512 + sub8;
        run_coh<32, 0>(lp, breg, acc);
      } else {                           // recurrent: h1(t-1)
        wave_wait_ge(relB, (unsigned)t);
        const u16* lp = h1buf + (size_t)((t + 1) & 1) * HBUF
                        + (size_t)arow * HH + (kq - 2) * 512 + sub8;
        run_coh<32, 0>(lp, breg, acc);
      }
      step_tail(acc, h1buf + (size_t)(t & 1) * HBUF, 0u, t == TT - 1,
                arrB, relB, t);
    }
  }
}

// out[b][c] = sum_k h1f[b][k] * Wd[c][k] + bd[c]   (all f32)
__global__ void dense_out(const float* __restrict__ h1, const float* __restrict__ Wd,
                          const float* __restrict__ bd, float* __restrict__ out)
{
  const int b  = threadIdx.x & 63;
  const int cl = threadIdx.x >> 6;
  const int cc = blockIdx.x * 4 + cl;    // class (250*4 = 1000)
  float acc = 0.f;
  const float* hrow = h1 + (size_t)b * HH;
  const float* wrow = Wd + (size_t)cc * HH;
#pragma unroll 8
  for (int k = 0; k < HH; k += 4) {
    f32x4 hv = *(const f32x4*)(hrow + k);
    f32x4 wv = *(const f32x4*)(wrow + k);
    acc += hv[0] * wv[0] + hv[1] * wv[1] + hv[2] * wv[2] + hv[3] * wv[3];
  }
  out[(size_t)b * NCLS + cc] = acc + bd[cc];
}

extern "C" void kernel_launch(void* const* d_in, const int* in_sizes, int n_in,
                              void* d_out, int out_size, void* d_ws, size_t ws_size,
                              hipStream_t stream)
{
  (void)in_sizes; (void)n_in; (void)out_size;
  const float* x    = (const float*)d_in[0];
  const float* Wih0 = (const float*)d_in[1];
  const float* Whh0 = (const float*)d_in[2];
  const float* bih0 = (const float*)d_in[3];
  const float* bhh0 = (const float*)d_in[4];
  const float* Wih1 = (const float*)d_in[5];
  const float* Whh1 = (const float*)d_in[6];
  const float* bih1 = (const float*)d_in[7];
  const float* bhh1 = (const float*)d_in[8];
  const float* Wd   = (const float*)d_in[9];
  const float* bd   = (const float*)d_in[10];

  unsigned* bar = (unsigned*)d_ws;                       // 8 KB flag/counter lines
  float* h1f  = (float*)((char*)d_ws + 8192);            // 256 KB
  u16* h1buf  = (u16*)((char*)d_ws + 272 * 1024);        // 2 x 128 KB
  u16* ring   = (u16*)((char*)d_ws + 528 * 1024);        // 3 x 128 KB
  u16* xb     = (u16*)((char*)d_ws + (1u << 20));        // 33.6 MB (tier A)

  const size_t needA = (1u << 20) + (size_t)BB * TT * II * 2;
  const bool tierA = (ws_size >= needA);

  // zero flags + h buffers every launch (graph-replay deterministic)
  hipMemsetAsync(d_ws, 0, 912 * 1024, stream);

  if (tierA) {
    hipLaunchKernelGGL(cvt_x, dim3(2048), dim3(256), 0, stream,
                       x, xb, (int)((size_t)BB * TT * II / 8));
    hipLaunchKernelGGL((lstm2_fused<true>), dim3(NBLK), dim3(BDIM), 0, stream,
                       x, xb, Wih0, Whh0, bih0, bhh0, Wih1, Whh1, bih1, bhh1,
                       ring, h1buf, h1f, bar);
  } else {
    hipLaunchKernelGGL((lstm2_fused<false>), dim3(NBLK), dim3(BDIM), 0, stream,
                       x, xb, Wih0, Whh0, bih0, bhh0, Wih1, Whh1, bih1, bhh1,
                       ring, h1buf, h1f, bar);
  }
  hipLaunchKernelGGL(dense_out, dim3(250), dim3(256), 0, stream, h1f, Wd, bd,
                     (float*)d_out);
}